// Round 1
// 211.807 us; speedup vs baseline: 1.0136x; 1.0136x over previous
//
#include <hip/hip_runtime.h>

// GCN on 100K nodes / 1.6M edges; output depends only on node_index's 3-hop
// in-neighborhood. v2: frontier-first, atomic-minimal.
//   F1 = in(n0) u {n0}   (~17)   -> rows in h2c (slot2/node2)
//   F2 = in(F1) u F1     (~290)  -> rows in h1c (slot1/node1)
//   S  = F2 u in(F2)     (~5K)   -> nodes whose degree we actually need
// deg histogram is restricted to S (need[] filter): ~80K atomics vs 1.6M.
// Active edges are bucketed per destination row during discovery scans, so
// the layer kernels are gather + plain store (no float atomics, no zeroed
// accumulator buffers).

#define HID  64
#define CAP1 2048   // compact rows for F2 (layer-1 outputs)
#define CAP2 512    // compact rows for F1 (layer-2 outputs)
#define RB1  128    // per-row in-edge bucket depth, layer 1
#define RB2  128    // per-row in-edge bucket depth, layer 2
#define CL3  2048   // layer-3 edge list capacity

__device__ __forceinline__ int ld_dst(const void* ei, int is64, int E, int e) {
  // int64 values are < 2^31: low dword suffices (halves scan read traffic)
  return is64 ? (int)((const unsigned*)ei)[((long long)E + e) << 1]
              : ((const int*)ei)[(long long)E + e];
}
__device__ __forceinline__ int ld_src(const void* ei, int is64, int e) {
  return is64 ? (int)((const unsigned*)ei)[(long long)e << 1]
              : ((const int*)ei)[e];
}

__global__ void k_init(int N, const unsigned* e32, int* flag, int* deg, int* need,
                       int* slot1, int* slot2, int* rc1, int* rc2,
                       int* cnt1, int* cnt2, int* ec3) {
  int i = blockIdx.x * blockDim.x + threadIdx.x;
  if (i < N) { deg[i] = 0; need[i] = 0; slot1[i] = -1; slot2[i] = -1; }
  if (i < CAP1) rc1[i] = 0;
  if (i < CAP2) rc2[i] = 0;
  if (i == 0) {
    *cnt1 = 0; *cnt2 = 0; *ec3 = 0;
    int is64 = 1;
    for (int k = 0; k < 64; ++k)
      if (e32[2 * k + 1] != 0u) { is64 = 0; break; }
    *flag = is64;
  }
}

// F1 discovery: src of edges whose dst == node_index; also collect layer-3
// edge list (one entry per edge occurrence — multi-edges count).
__global__ void k_scanF1(const void* ei, int E, const int* flag, const int* nidx_p,
                         int* slot2, int* node2, int* cnt2, int* l3, int* ec3) {
  int e = blockIdx.x * blockDim.x + threadIdx.x;
  if (e >= E) return;
  int is64 = *flag;
  int d = ld_dst(ei, is64, E, e);
  if (d == *nidx_p) {
    int s = ld_src(ei, is64, e);
    if (atomicCAS(&slot2[s], -1, -2) == -1) {
      int p = atomicAdd(cnt2, 1) & (CAP2 - 1);
      slot2[s] = p; node2[p] = s;
    }
    int q = atomicAdd(ec3, 1) & (CL3 - 1);
    l3[q] = s;
  }
}

// seed n0 into F1; propagate F1 -> F2 rows; mark need for F1. One block.
__global__ void k_seed(const int* nidx_p, int* slot1, int* slot2,
                       int* node1, int* node2, int* need, int* cnt1, int* cnt2) {
  __shared__ int rows;
  if (threadIdx.x == 0) {
    int n = *nidx_p;
    if (atomicCAS(&slot2[n], -1, -2) == -1) {
      int p = atomicAdd(cnt2, 1) & (CAP2 - 1);
      slot2[n] = p; node2[p] = n;
    }
    rows = min(*cnt2, CAP2);
  }
  __syncthreads();
  for (int r = threadIdx.x; r < rows; r += blockDim.x) {
    int i = node2[r];
    need[i] = 1;
    if (atomicCAS(&slot1[i], -1, -2) == -1) {
      int p = atomicAdd(cnt1, 1) & (CAP1 - 1);
      slot1[i] = p; node1[p] = i;
    }
  }
}

// F2 discovery: edges with dst in F1. Claim slot1 rows, mark need, and bucket
// the edge under its destination's F1 row (layer-2 in-edge list).
__global__ void k_scanF2(const void* ei, int E, const int* flag,
                         const int* slot2, int* slot1, int* node1, int* need,
                         int* cnt1, int* rc2, int* bl2) {
  int e = blockIdx.x * blockDim.x + threadIdx.x;
  if (e >= E) return;
  int is64 = *flag;
  int d = ld_dst(ei, is64, E, e);
  int ad = slot2[d];
  if (ad >= 0) {
    int s = ld_src(ei, is64, e);
    need[s] = 1;
    if (atomicCAS(&slot1[s], -1, -2) == -1) {
      int p = atomicAdd(cnt1, 1) & (CAP1 - 1);
      slot1[s] = p; node1[p] = s;
    }
    int q = atomicAdd(&rc2[ad], 1);
    if (q < RB2) bl2[ad * RB2 + q] = s;
  }
}

// S marking + layer-1 in-edge buckets: edges with dst in F2.
__global__ void k_scanS(const void* ei, int E, const int* flag,
                        const int* slot1, int* need, int* rc1, int* bl1) {
  int e = blockIdx.x * blockDim.x + threadIdx.x;
  if (e >= E) return;
  int is64 = *flag;
  int d = ld_dst(ei, is64, E, e);
  int ad = slot1[d];
  if (ad >= 0) {
    int s = ld_src(ei, is64, e);
    need[s] = 1;
    int q = atomicAdd(&rc1[ad], 1);
    if (q < RB1) bl1[ad * RB1 + q] = s;
  }
}

// degree count restricted to needed nodes (~80K atomics over ~5K addresses)
__global__ void k_scanDeg(const void* ei, int E, const int* flag,
                          const int* need, int* deg) {
  int e = blockIdx.x * blockDim.x + threadIdx.x;
  if (e >= E) return;
  int is64 = *flag;
  int d = ld_dst(ei, is64, E, e);
  if (need[d]) atomicAdd(&deg[d], 1);
}

// fused layer-1 aggregate + finalize: one wave per F2 row, gather in-edges
// from the bucket, accumulate in registers, one plain store. No atomics.
__global__ void k_l1(const float* x, const float* W1, const float* b1,
                     const int* deg, const int* node1, const int* cnt1,
                     const int* rc1, const int* bl1, float* h1c) {
  int w = (blockIdx.x * blockDim.x + threadIdx.x) >> 6;
  int lane = threadIdx.x & 63;
  int rows = min(*cnt1, CAP1);
  if (w >= rows) return;
  int i = node1[w];
  float di = 1.0f / sqrtf((float)(deg[i] + 1));
  float wc0 = W1[0 * HID + lane], wc1 = W1[1 * HID + lane];
  float wc2 = W1[2 * HID + lane], wc3 = W1[3 * HID + lane];
  int cnt = min(rc1[w], RB1);
  float acc = 0.f;
  for (int j = 0; j < cnt; ++j) {
    int s = bl1[w * RB1 + j];
    float c = (1.0f / sqrtf((float)(deg[s] + 1))) * di;
    float m = x[s * 4 + 0] * wc0 + x[s * 4 + 1] * wc1 +
              x[s * 4 + 2] * wc2 + x[s * 4 + 3] * wc3;
    acc += c * m;
  }
  float m0 = x[i * 4 + 0] * wc0 + x[i * 4 + 1] * wc1 +
             x[i * 4 + 2] * wc2 + x[i * 4 + 3] * wc3;
  acc += di * di * m0;  // self loop
  float v = acc + b1[lane];
  h1c[w * HID + lane] = v > 0.f ? v : 0.f;
}

// fused layer-2 aggregate + finalize: one wave per F1 row.
__global__ void k_l2(const float* W2, const float* b2, const int* deg,
                     const int* node2, const int* cnt2, const int* slot1,
                     const int* rc2, const int* bl2, const float* h1c, float* h2c) {
  int w = (blockIdx.x * blockDim.x + threadIdx.x) >> 6;
  int lane = threadIdx.x & 63;
  int rows = min(*cnt2, CAP2);
  if (w >= rows) return;
  int i = node2[w];
  float di = 1.0f / sqrtf((float)(deg[i] + 1));
  int cnt = min(rc2[w], RB2);
  float acc = 0.f;
  for (int j = 0; j < cnt; ++j) {
    int s = bl2[w * RB2 + j];
    float c = (1.0f / sqrtf((float)(deg[s] + 1))) * di;
    const float* hr = &h1c[slot1[s] * HID];
    float m = 0.f;
#pragma unroll 16
    for (int k = 0; k < HID; ++k) m += hr[k] * W2[k * HID + lane];
    acc += c * m;
  }
  {
    const float* hr = &h1c[slot1[i] * HID];  // self loop (i in F2 by seed)
    float m = 0.f;
#pragma unroll 16
    for (int k = 0; k < HID; ++k) m += hr[k] * W2[k * HID + lane];
    acc += di * di * m;
  }
  float v = acc + b2[lane];
  h2c[w * HID + lane] = v > 0.f ? v : 0.f;
}

// layer-3 aggregate (over l3 list) + head MLP + 4 projections. One block.
__global__ void k_tail(const int* nidx_p, const int* slot2, const int* deg,
                       const float* h2c, const int* l3, const int* ec3,
                       const float* W3, const float* b3,
                       const float* Wp, const float* bp,
                       const float* Wa, const float* ba,
                       const float* Wm, const float* bm,
                       const float* Wg, const float* bg,
                       const float* Wt, const float* bt, float* out) {
  __shared__ float part[4][HID];
  __shared__ float h3[HID];
  __shared__ float p[HID];
  int tid = threadIdx.x, wv = tid >> 6, lane = tid & 63;
  int nidx = *nidx_p;
  float dn = 1.0f / sqrtf((float)(deg[nidx] + 1));
  int cnt = min(*ec3, CL3);
  float acc = 0.f;
  for (int j = wv; j < cnt; j += 4) {
    int s = l3[j];
    float c = (1.0f / sqrtf((float)(deg[s] + 1))) * dn;
    const float* hr = &h2c[slot2[s] * HID];
    float m = 0.f;
#pragma unroll 16
    for (int k = 0; k < HID; ++k) m += hr[k] * W3[k * HID + lane];
    acc += c * m;
  }
  part[wv][lane] = acc;
  __syncthreads();
  if (wv == 0) {
    float a = part[0][lane] + part[1][lane] + part[2][lane] + part[3][lane];
    const float* hr = &h2c[slot2[nidx] * HID];
    float m = 0.f;
#pragma unroll 16
    for (int k = 0; k < HID; ++k) m += hr[k] * W3[k * HID + lane];
    float v = a + dn * dn * m + b3[lane];
    h3[lane] = v > 0.f ? v : 0.f;
  }
  __syncthreads();
  if (wv == 0) {
    float pv = bp[lane];
#pragma unroll 16
    for (int k = 0; k < HID; ++k) pv += h3[k] * Wp[k * HID + lane];
    p[lane] = pv > 0.f ? pv : 0.f;
  }
  __syncthreads();
  if (tid < 4) {
    float o = ba[tid];
    for (int k = 0; k < HID; ++k) o += p[k] * Wa[k * 4 + tid];
    out[tid] = o;
  } else if (tid < 6) {
    int c = tid - 4; float o = bm[c];
    for (int k = 0; k < HID; ++k) o += p[k] * Wm[k * 2 + c];
    out[tid] = o;
  } else if (tid < 9) {
    int c = tid - 6; float o = bg[c];
    for (int k = 0; k < HID; ++k) o += p[k] * Wg[k * 3 + c];
    out[tid] = o;
  } else if (tid < 19) {
    int c = tid - 9; float o = bt[c];
    for (int k = 0; k < HID; ++k) o += p[k] * Wt[k * 10 + c];
    out[tid] = o;
  }
}

extern "C" void kernel_launch(void* const* d_in, const int* in_sizes, int n_in,
                              void* d_out, int out_size, void* d_ws, size_t ws_size,
                              hipStream_t stream) {
  const float* x  = (const float*)d_in[0];
  const void*  ei = d_in[1];
  const int* nidx = (const int*)d_in[2];
  const float* W1 = (const float*)d_in[3];
  const float* b1 = (const float*)d_in[4];
  const float* W2 = (const float*)d_in[5];
  const float* b2 = (const float*)d_in[6];
  const float* W3 = (const float*)d_in[7];
  const float* b3 = (const float*)d_in[8];
  const float* Wp = (const float*)d_in[9];
  const float* bp = (const float*)d_in[10];
  const float* Wa = (const float*)d_in[11];
  const float* ba = (const float*)d_in[12];
  const float* Wm = (const float*)d_in[13];
  const float* bm = (const float*)d_in[14];
  const float* Wg = (const float*)d_in[15];
  const float* bg = (const float*)d_in[16];
  const float* Wt = (const float*)d_in[17];
  const float* bt = (const float*)d_in[18];
  float* out = (float*)d_out;

  int N = in_sizes[0] / 4;   // 100000
  int E = in_sizes[1] / 2;   // 1600000

  char* w = (char*)d_ws;
  size_t o = 0;
  auto take = [&](size_t bytes) -> void* {
    void* p = w + o;
    o += (bytes + 255) & ~(size_t)255;
    return p;
  };
  int*   flag  = (int*)take(4);
  int*   cnt1  = (int*)take(4);
  int*   cnt2  = (int*)take(4);
  int*   ec3   = (int*)take(4);
  int*   deg   = (int*)take((size_t)N * 4);
  int*   need  = (int*)take((size_t)N * 4);
  int*   slot1 = (int*)take((size_t)N * 4);
  int*   slot2 = (int*)take((size_t)N * 4);
  int*   node1 = (int*)take((size_t)CAP1 * 4);
  int*   node2 = (int*)take((size_t)CAP2 * 4);
  int*   rc1   = (int*)take((size_t)CAP1 * 4);
  int*   rc2   = (int*)take((size_t)CAP2 * 4);
  int*   bl1   = (int*)take((size_t)CAP1 * RB1 * 4);
  int*   bl2   = (int*)take((size_t)CAP2 * RB2 * 4);
  int*   l3    = (int*)take((size_t)CL3 * 4);
  float* h1c   = (float*)take((size_t)CAP1 * HID * 4);
  float* h2c   = (float*)take((size_t)CAP2 * HID * 4);

  int gE = (E + 255) / 256;
  int gN = (N + 255) / 256;

  k_init   <<<gN, 256, 0, stream>>>(N, (const unsigned*)ei, flag, deg, need,
                                    slot1, slot2, rc1, rc2, cnt1, cnt2, ec3);
  k_scanF1 <<<gE, 256, 0, stream>>>(ei, E, flag, nidx, slot2, node2, cnt2, l3, ec3);
  k_seed   <<<1, 256, 0, stream>>>(nidx, slot1, slot2, node1, node2, need, cnt1, cnt2);
  k_scanF2 <<<gE, 256, 0, stream>>>(ei, E, flag, slot2, slot1, node1, need, cnt1, rc2, bl2);
  k_scanS  <<<gE, 256, 0, stream>>>(ei, E, flag, slot1, need, rc1, bl1);
  k_scanDeg<<<gE, 256, 0, stream>>>(ei, E, flag, need, deg);
  k_l1     <<<(CAP1 * HID) / 256, 256, 0, stream>>>(x, W1, b1, deg, node1, cnt1, rc1, bl1, h1c);
  k_l2     <<<(CAP2 * HID) / 256, 256, 0, stream>>>(W2, b2, deg, node2, cnt2, slot1, rc2, bl2, h1c, h2c);
  k_tail   <<<1, 256, 0, stream>>>(nidx, slot2, deg, h2c, l3, ec3, W3, b3, Wp, bp,
                                   Wa, ba, Wm, bm, Wg, bg, Wt, bt, out);
}

// Round 2
// 165.428 us; speedup vs baseline: 1.2978x; 1.2804x over previous
//
#include <hip/hip_runtime.h>

// GCN on 100K nodes / 1.6M edges; output depends only on node_index's 3-hop
// in-neighborhood. v3: latency-focused.
//   F1 = in(n0) u {n0}   (~17)   -> rows in h2c (slot2/node2)
//   F2 = in(F1) u F1     (~290)  -> rows in h1c (slot1/node1)
//   S  = F2 u in(F2)     (~5K)   -> nodes whose degree we need
// Changes vs v2 (which had k_l2 = 51 us: 17 waves each on a serial
// dependent-load chain):
//  - layer kernels factorized: accumulate sum_e c_e * h_src FIRST (cheap
//    AXPY per edge), then ONE matvec per row. 16x less work, short chains.
//  - per-row edge metadata loaded lane-parallel then shfl/LDS-broadcast:
//    per-edge row loads become independent (latency overlapped).
//  - k_init replaced by two hipMemsetAsync (0x00 zeros, 0xFF slot maps).
//  - scans vectorized: 8 edges/thread, dst-only reads (src on hit).

#define HID  64
#define CAP1 2048   // compact rows for F2 (layer-1 outputs)
#define CAP2 512    // compact rows for F1 (layer-2 outputs)
#define RB1  128    // per-row in-edge bucket depth, layer 1
#define RB2  128    // per-row in-edge bucket depth, layer 2
#define CL3  2048   // layer-3 edge list capacity
#define VE   8      // edges per thread in scans

__device__ __forceinline__ int ld_src(const void* ei, int is64, long long e) {
  return is64 ? (int)((const unsigned*)ei)[e << 1] : ((const int*)ei)[e];
}

// load up to VE dst values starting at edge `base`; returns count
__device__ __forceinline__ int load_dsts(const void* ei, long long E, long long base,
                                         int is64, int d[VE]) {
  int n = (int)((E - base) < VE ? (E - base) : VE);
  if (is64) {
    const unsigned long long* p = (const unsigned long long*)ei + E + base;
    if (n == VE && (((E + base) & 1) == 0)) {
      const ulonglong2* q = (const ulonglong2*)p;
#pragma unroll
      for (int k = 0; k < VE / 2; ++k) {
        ulonglong2 v = q[k];
        d[2 * k] = (int)(unsigned)v.x; d[2 * k + 1] = (int)(unsigned)v.y;
      }
    } else {
      for (int k = 0; k < n; ++k) d[k] = (int)(unsigned)p[k];
    }
  } else {
    const int* p = (const int*)ei + E + base;
    if (n == VE && (((E + base) & 3) == 0)) {
      const int4* q = (const int4*)p;
#pragma unroll
      for (int k = 0; k < VE / 4; ++k) {
        int4 v = q[k];
        d[4 * k] = v.x; d[4 * k + 1] = v.y; d[4 * k + 2] = v.z; d[4 * k + 3] = v.w;
      }
    } else {
      for (int k = 0; k < n; ++k) d[k] = p[k];
    }
  }
  return n;
}

__global__ void k_detect(const unsigned* e32, int* flag) {
  if (blockIdx.x == 0 && threadIdx.x == 0) {
    int is64 = 1;
    for (int k = 0; k < 64; ++k)
      if (e32[2 * k + 1] != 0u) { is64 = 0; break; }
    *flag = is64;
  }
}

// F1 discovery: src of edges whose dst == node_index; collect layer-3 list.
__global__ void k_scanF1(const void* ei, int E, const int* flag, const int* nidx_p,
                         int* slot2, int* node2, int* cnt2, int* l3, int* ec3) {
  long long base = ((long long)blockIdx.x * blockDim.x + threadIdx.x) * VE;
  if (base >= E) return;
  int is64 = *flag, nidx = *nidx_p;
  int d[VE];
  int n = load_dsts(ei, E, base, is64, d);
  for (int k = 0; k < n; ++k) {
    if (d[k] == nidx) {
      int s = ld_src(ei, is64, base + k);
      if (atomicCAS(&slot2[s], -1, -2) == -1) {
        int p = atomicAdd(cnt2, 1) & (CAP2 - 1);
        slot2[s] = p; node2[p] = s;
      }
      int q = atomicAdd(ec3, 1);
      if (q < CL3) l3[q] = s;
    }
  }
}

// seed n0 into F1; propagate F1 -> F2 rows; mark need for F1. One block.
__global__ void k_seed(const int* nidx_p, int* slot1, int* slot2,
                       int* node1, int* node2, int* need, int* cnt1, int* cnt2) {
  __shared__ int rows;
  if (threadIdx.x == 0) {
    int n = *nidx_p;
    if (atomicCAS(&slot2[n], -1, -2) == -1) {
      int p = atomicAdd(cnt2, 1) & (CAP2 - 1);
      slot2[n] = p; node2[p] = n;
    }
    rows = min(*cnt2, CAP2);
  }
  __syncthreads();
  for (int r = threadIdx.x; r < rows; r += blockDim.x) {
    int i = node2[r];
    need[i] = 1;
    if (atomicCAS(&slot1[i], -1, -2) == -1) {
      int p = atomicAdd(cnt1, 1) & (CAP1 - 1);
      slot1[i] = p; node1[p] = i;
    }
  }
}

// F2 discovery: edges with dst in F1 -> claim slot1, mark need, bucket by row.
__global__ void k_scanF2(const void* ei, int E, const int* flag,
                         const int* slot2, int* slot1, int* node1, int* need,
                         int* cnt1, int* rc2, int* bl2) {
  long long base = ((long long)blockIdx.x * blockDim.x + threadIdx.x) * VE;
  if (base >= E) return;
  int is64 = *flag;
  int d[VE];
  int n = load_dsts(ei, E, base, is64, d);
  for (int k = 0; k < n; ++k) {
    int ad = slot2[d[k]];
    if (ad >= 0) {
      int s = ld_src(ei, is64, base + k);
      need[s] = 1;
      if (atomicCAS(&slot1[s], -1, -2) == -1) {
        int p = atomicAdd(cnt1, 1) & (CAP1 - 1);
        slot1[s] = p; node1[p] = s;
      }
      int q = atomicAdd(&rc2[ad], 1);
      if (q < RB2) bl2[ad * RB2 + q] = s;
    }
  }
}

// S marking + layer-1 buckets: edges with dst in F2.
__global__ void k_scanS(const void* ei, int E, const int* flag,
                        const int* slot1, int* need, int* rc1, int* bl1) {
  long long base = ((long long)blockIdx.x * blockDim.x + threadIdx.x) * VE;
  if (base >= E) return;
  int is64 = *flag;
  int d[VE];
  int n = load_dsts(ei, E, base, is64, d);
  for (int k = 0; k < n; ++k) {
    int ad = slot1[d[k]];
    if (ad >= 0) {
      int s = ld_src(ei, is64, base + k);
      need[s] = 1;
      int q = atomicAdd(&rc1[ad], 1);
      if (q < RB1) bl1[ad * RB1 + q] = s;
    }
  }
}

// degree count restricted to needed nodes (~80K atomics over ~5K addresses)
__global__ void k_scanDeg(const void* ei, int E, const int* flag,
                          const int* need, int* deg) {
  long long base = ((long long)blockIdx.x * blockDim.x + threadIdx.x) * VE;
  if (base >= E) return;
  int is64 = *flag;
  int d[VE];
  int n = load_dsts(ei, E, base, is64, d);
  for (int k = 0; k < n; ++k)
    if (need[d[k]]) atomicAdd(&deg[d[k]], 1);
}

// layer 1, one wave per F2 row. Factorized: g = sum_e c_e*x[s] + di^2*x[i]
// (lane-parallel over edges, butterfly reduce), then h1 = relu(g @ W1 + b1).
__global__ void k_l1(const float* __restrict__ x, const float* __restrict__ W1,
                     const float* __restrict__ b1, const int* __restrict__ deg,
                     const int* __restrict__ node1, const int* __restrict__ cnt1,
                     const int* __restrict__ rc1, const int* __restrict__ bl1,
                     float* __restrict__ h1c) {
  int w = blockIdx.x * 4 + (threadIdx.x >> 6);
  int lane = threadIdx.x & 63;
  int rows = min(*cnt1, CAP1);
  if (w >= rows) return;
  int i = node1[w];
  float di = 1.0f / sqrtf((float)(deg[i] + 1));
  int cnt = min(rc1[w], RB1);
  float ax = 0.f, ay = 0.f, az = 0.f, aw = 0.f;
  for (int j = lane; j < cnt; j += 64) {
    int s = bl1[w * RB1 + j];
    float c = (1.0f / sqrtf((float)(deg[s] + 1))) * di;
    float4 xv = ((const float4*)x)[s];
    ax += c * xv.x; ay += c * xv.y; az += c * xv.z; aw += c * xv.w;
  }
#pragma unroll
  for (int t = 1; t < 64; t <<= 1) {
    ax += __shfl_xor(ax, t); ay += __shfl_xor(ay, t);
    az += __shfl_xor(az, t); aw += __shfl_xor(aw, t);
  }
  float4 xi = ((const float4*)x)[i];
  float dd = di * di;
  ax += dd * xi.x; ay += dd * xi.y; az += dd * xi.z; aw += dd * xi.w;
  float v = ax * W1[lane] + ay * W1[64 + lane] + az * W1[128 + lane] +
            aw * W1[192 + lane] + b1[lane];
  h1c[w * HID + lane] = v > 0.f ? v : 0.f;
}

// layer 2, one wave per F1 row. Meta loaded lane-parallel, shfl-broadcast so
// the per-edge h1 row loads are independent; then one matvec via LDS.
__global__ void k_l2(const float* __restrict__ W2, const float* __restrict__ b2,
                     const int* __restrict__ deg, const int* __restrict__ node2,
                     const int* __restrict__ cnt2, const int* __restrict__ slot1,
                     const int* __restrict__ rc2, const int* __restrict__ bl2,
                     const float* __restrict__ h1c, float* __restrict__ h2c) {
  __shared__ float sh[4][HID];
  int wv = threadIdx.x >> 6, lane = threadIdx.x & 63;
  int w = blockIdx.x * 4 + wv;
  int rows = min(*cnt2, CAP2);
  if (w >= rows) return;
  int i = node2[w];
  float di = 1.0f / sqrtf((float)(deg[i] + 1));
  int cnt = min(rc2[w], RB2);
  float acc = 0.f;
  for (int j0 = 0; j0 < cnt; j0 += 64) {
    int nb = min(64, cnt - j0);
    int sl = 0; float c = 0.f;
    if (lane < nb) {
      int s = bl2[w * RB2 + j0 + lane];
      sl = slot1[s];
      c = (1.0f / sqrtf((float)(deg[s] + 1))) * di;
    }
    for (int j = 0; j < nb; ++j) {
      int slj = __shfl(sl, j);
      float cj = __shfl(c, j);
      acc += cj * h1c[slj * HID + lane];
    }
  }
  acc += di * di * h1c[slot1[i] * HID + lane];
  sh[wv][lane] = acc;  // same-wave write->read (lockstep), no barrier needed
  float v = b2[lane];
#pragma unroll 16
  for (int k = 0; k < HID; ++k) v += sh[wv][k] * W2[k * HID + lane];
  h2c[w * HID + lane] = v > 0.f ? v : 0.f;
}

// layer-3 aggregate (factorized) + head MLP + 4 projections. One block.
__global__ void k_tail(const int* nidx_p, const int* slot2, const int* deg,
                       const float* h2c, const int* l3, const int* ec3,
                       const float* W3, const float* b3,
                       const float* Wp, const float* bp,
                       const float* Wa, const float* ba,
                       const float* Wm, const float* bm,
                       const float* Wg, const float* bg,
                       const float* Wt, const float* bt, float* out) {
  __shared__ float part[4][HID];
  __shared__ float g3[HID];
  __shared__ float h3[HID];
  __shared__ float p[HID];
  __shared__ int   ssl[64];
  __shared__ float scc[64];
  int tid = threadIdx.x, wv = tid >> 6, lane = tid & 63;
  int nidx = *nidx_p;
  float dn = 1.0f / sqrtf((float)(deg[nidx] + 1));
  int cnt = min(*ec3, CL3);
  float acc = 0.f;
  for (int j0 = 0; j0 < cnt; j0 += 64) {
    int nb = min(64, cnt - j0);
    if (tid < nb) {
      int s = l3[j0 + tid];
      ssl[tid] = slot2[s];
      scc[tid] = (1.0f / sqrtf((float)(deg[s] + 1))) * dn;
    }
    __syncthreads();
    for (int j = wv; j < nb; j += 4)
      acc += scc[j] * h2c[ssl[j] * HID + lane];
    __syncthreads();
  }
  part[wv][lane] = acc;
  __syncthreads();
  if (wv == 0) {
    float a = part[0][lane] + part[1][lane] + part[2][lane] + part[3][lane];
    a += dn * dn * h2c[slot2[nidx] * HID + lane];
    g3[lane] = a;
  }
  __syncthreads();
  if (wv == 0) {
    float v = b3[lane];
#pragma unroll 16
    for (int k = 0; k < HID; ++k) v += g3[k] * W3[k * HID + lane];
    h3[lane] = v > 0.f ? v : 0.f;
  }
  __syncthreads();
  if (wv == 0) {
    float pv = bp[lane];
#pragma unroll 16
    for (int k = 0; k < HID; ++k) pv += h3[k] * Wp[k * HID + lane];
    p[lane] = pv > 0.f ? pv : 0.f;
  }
  __syncthreads();
  if (tid < 4) {
    float o = ba[tid];
    for (int k = 0; k < HID; ++k) o += p[k] * Wa[k * 4 + tid];
    out[tid] = o;
  } else if (tid < 6) {
    int c = tid - 4; float o = bm[c];
    for (int k = 0; k < HID; ++k) o += p[k] * Wm[k * 2 + c];
    out[tid] = o;
  } else if (tid < 9) {
    int c = tid - 6; float o = bg[c];
    for (int k = 0; k < HID; ++k) o += p[k] * Wg[k * 3 + c];
    out[tid] = o;
  } else if (tid < 19) {
    int c = tid - 9; float o = bt[c];
    for (int k = 0; k < HID; ++k) o += p[k] * Wt[k * 10 + c];
    out[tid] = o;
  }
}

extern "C" void kernel_launch(void* const* d_in, const int* in_sizes, int n_in,
                              void* d_out, int out_size, void* d_ws, size_t ws_size,
                              hipStream_t stream) {
  const float* x  = (const float*)d_in[0];
  const void*  ei = d_in[1];
  const int* nidx = (const int*)d_in[2];
  const float* W1 = (const float*)d_in[3];
  const float* b1 = (const float*)d_in[4];
  const float* W2 = (const float*)d_in[5];
  const float* b2 = (const float*)d_in[6];
  const float* W3 = (const float*)d_in[7];
  const float* b3 = (const float*)d_in[8];
  const float* Wp = (const float*)d_in[9];
  const float* bp = (const float*)d_in[10];
  const float* Wa = (const float*)d_in[11];
  const float* ba = (const float*)d_in[12];
  const float* Wm = (const float*)d_in[13];
  const float* bm = (const float*)d_in[14];
  const float* Wg = (const float*)d_in[15];
  const float* bg = (const float*)d_in[16];
  const float* Wt = (const float*)d_in[17];
  const float* bt = (const float*)d_in[18];
  float* out = (float*)d_out;

  int N = in_sizes[0] / 4;   // 100000
  int E = in_sizes[1] / 2;   // 1600000

  char* w = (char*)d_ws;
  size_t o = 0;
  auto take = [&](size_t bytes) -> void* {
    void* p = w + o;
    o += (bytes + 255) & ~(size_t)255;
    return p;
  };
  // zero region (one memset): cnt1, cnt2, ec3, deg, need, rc1, rc2
  size_t zeroBytes = (size_t)(3 + 2 * N + CAP1 + CAP2) * 4;
  int* zr = (int*)take(zeroBytes);
  int* cnt1 = zr + 0;
  int* cnt2 = zr + 1;
  int* ec3  = zr + 2;
  int* deg  = zr + 3;
  int* need = deg + N;
  int* rc1  = need + N;
  int* rc2  = rc1 + CAP1;
  // 0xFF region (one memset): slot1, slot2  (-1 == all ones)
  int* slots = (int*)take((size_t)2 * N * 4);
  int* slot1 = slots;
  int* slot2 = slots + N;
  int*   flag  = (int*)take(4);
  int*   node1 = (int*)take((size_t)CAP1 * 4);
  int*   node2 = (int*)take((size_t)CAP2 * 4);
  int*   bl1   = (int*)take((size_t)CAP1 * RB1 * 4);
  int*   bl2   = (int*)take((size_t)CAP2 * RB2 * 4);
  int*   l3    = (int*)take((size_t)CL3 * 4);
  float* h1c   = (float*)take((size_t)CAP1 * HID * 4);
  float* h2c   = (float*)take((size_t)CAP2 * HID * 4);

  int gS = (int)(((long long)E + 256 * VE - 1) / (256 * VE));

  hipMemsetAsync(zr, 0x00, zeroBytes, stream);
  hipMemsetAsync(slots, 0xFF, (size_t)2 * N * 4, stream);
  k_detect <<<1, 64, 0, stream>>>((const unsigned*)ei, flag);
  k_scanF1 <<<gS, 256, 0, stream>>>(ei, E, flag, nidx, slot2, node2, cnt2, l3, ec3);
  k_seed   <<<1, 256, 0, stream>>>(nidx, slot1, slot2, node1, node2, need, cnt1, cnt2);
  k_scanF2 <<<gS, 256, 0, stream>>>(ei, E, flag, slot2, slot1, node1, need, cnt1, rc2, bl2);
  k_scanS  <<<gS, 256, 0, stream>>>(ei, E, flag, slot1, need, rc1, bl1);
  k_scanDeg<<<gS, 256, 0, stream>>>(ei, E, flag, need, deg);
  k_l1     <<<CAP1 / 4, 256, 0, stream>>>(x, W1, b1, deg, node1, cnt1, rc1, bl1, h1c);
  k_l2     <<<CAP2 / 4, 256, 0, stream>>>(W2, b2, deg, node2, cnt2, slot1, rc2, bl2, h1c, h2c);
  k_tail   <<<1, 256, 0, stream>>>(nidx, slot2, deg, h2c, l3, ec3, W3, b3, Wp, bp,
                                   Wa, ba, Wm, bm, Wg, bg, Wt, bt, out);
}